// Round 12
// baseline (304.476 us; speedup 1.0000x reference)
//
#include <hip/hip_runtime.h>
#include <hip/hip_bf16.h>

typedef short v8s __attribute__((ext_vector_type(8)));
typedef float v4f __attribute__((ext_vector_type(4)));

#define MFMA16(a, b, c) __builtin_amdgcn_mfma_f32_16x16x32_bf16((a), (b), (c), 0, 0, 0)

constexpr int Bsz   = 128;
constexpr int Lq    = 32;
constexpr int Ld    = 512;
constexpr int H     = 768;
constexpr int D     = 128;
constexpr int QROWS = Bsz * Lq;          // 4096
constexpr int DROWS = Bsz * Ld;          // 65536
constexpr int MTOT  = QROWS + 2 * DROWS; // 135168
constexpr int NG    = MTOT / 32;         // 4224 row-groups of 32
static_assert(QROWS % 32 == 0 && DROWS % 32 == 0, "groups never span sources");

// f32 -> bf16 bits, round-to-nearest-even
static __device__ __forceinline__ unsigned short f2b(float f) {
    unsigned int u = __builtin_bit_cast(unsigned int, f);
    unsigned int r = u + 0x7FFFu + ((u >> 16) & 1u);
    return (unsigned short)(r >> 16);
}
static __device__ __forceinline__ v8s mk8(float4 f0, float4 f1) {
    v8s a;
    a[0] = (short)f2b(f0.x); a[1] = (short)f2b(f0.y);
    a[2] = (short)f2b(f0.z); a[3] = (short)f2b(f0.w);
    a[4] = (short)f2b(f1.x); a[5] = (short)f2b(f1.y);
    a[6] = (short)f2b(f1.z); a[7] = (short)f2b(f1.w);
    return a;
}

// ---------------------------------------------------------------------------
// Kernel 1: Wt[d][h] = bf16(W[h][d])
// ---------------------------------------------------------------------------
__global__ void prep_w_kernel(const float* __restrict__ W,
                              unsigned short* __restrict__ Wt) {
    int idx = blockIdx.x * 256 + threadIdx.x;
    if (idx < H * D) {
        int d = idx / H, h = idx % H;
        Wt[idx] = f2b(W[h * D + d]);
    }
}

// ---------------------------------------------------------------------------
// Kernel 2: projection — barrier-free persistent GEMM.
//   768 thr = 12 waves = 4 D-slices (32 cols) x 3 K-thirds (256 k).
//   Each wave pins its Wt slice in 16 v8s registers (loaded ONCE per kernel,
//   anti-sinking asm fences). Inner loop per 32-row group: 8 K-steps of
//   {4 float4 A-loads + 2 cvt + 4 MFMA} — NO barriers, NO LDS, NO W loads;
//   waves run free like the R7 probe (which hit ~4.5 TB/s).
//   K-thirds combined in LDS per group (epilogue-only syncthreads), then
//   bias/L2-norm/mask/store. Persistent: grid=256, block strides row-groups.
// ---------------------------------------------------------------------------
__global__ __launch_bounds__(768, 3) void proj_norm_kernel(
    const float* __restrict__ qh, const float* __restrict__ pdh,
    const float* __restrict__ ndh, const float* __restrict__ bias,
    const int* __restrict__ pdm, const int* __restrict__ ndm,
    const unsigned short* __restrict__ Wt, unsigned short* __restrict__ emb)
{
    __shared__ float P[32][132];   // combine buffer, padded (2-way max)

    const int tid  = threadIdx.x;
    const int lane = tid & 63, wave = tid >> 6;   // 0..11
    const int l15  = lane & 15, lg = lane >> 4;
    const int dg   = wave & 3;                    // D-slice: cols [32dg,32dg+32)
    const int kg   = wave >> 2;                   // K-third: k in [256kg,256kg+256)

    // ---- W prologue: load once, pin in registers (anti-sinking fence) ----
    const unsigned short* wp = Wt + (size_t)(dg * 32 + l15) * H + kg * 256 + lg * 8;
    v8s w[16];                                     // w[nt*8+ks]
#pragma unroll
    for (int nt = 0; nt < 2; ++nt)
#pragma unroll
        for (int ks = 0; ks < 8; ++ks)
            w[nt * 8 + ks] = *(const v8s*)(wp + (size_t)nt * 16 * H + ks * 32);
#pragma unroll
    for (int i = 0; i < 16; ++i)
        asm volatile("" : "+v"(w[i]));             // values must exist HERE

    const float bv0 = bias[dg * 32 + l15];
    const float bv1 = bias[dg * 32 + 16 + l15];

    for (int g = blockIdx.x; g < NG; g += gridDim.x) {
        const long row0 = (long)g * 32;
        const float* src; const int* mask; long srow;
        if (row0 < QROWS)              { src = qh;  srow = row0;                 mask = nullptr; }
        else if (row0 < QROWS + DROWS) { src = pdh; srow = row0 - QROWS;         mask = pdm; }
        else                           { src = ndh; srow = row0 - QROWS - DROWS; mask = ndm; }

        const float* ap = src + (srow + l15) * (long)H + kg * 256 + lg * 8;

        v4f acc[2][2];
#pragma unroll
        for (int mt = 0; mt < 2; ++mt)
#pragma unroll
            for (int nt = 0; nt < 2; ++nt) acc[mt][nt] = (v4f){0.f, 0.f, 0.f, 0.f};

        // ---- free-running A stream: 8 K-steps, no sync of any kind ----
#pragma unroll
        for (int ks = 0; ks < 8; ++ks) {
            float4 f00 = *(const float4*)(ap + ks * 32);
            float4 f01 = *(const float4*)(ap + ks * 32 + 4);
            float4 f10 = *(const float4*)(ap + (size_t)16 * H + ks * 32);
            float4 f11 = *(const float4*)(ap + (size_t)16 * H + ks * 32 + 4);
            v8s a0 = mk8(f00, f01);
            v8s a1 = mk8(f10, f11);
            acc[0][0] = MFMA16(a0, w[ks],     acc[0][0]);
            acc[0][1] = MFMA16(a0, w[8 + ks], acc[0][1]);
            acc[1][0] = MFMA16(a1, w[ks],     acc[1][0]);
            acc[1][1] = MFMA16(a1, w[8 + ks], acc[1][1]);
        }

        // ---- combine the 3 K-thirds in LDS (epilogue-only barriers) ----
        if (kg == 0) {
#pragma unroll
            for (int mt = 0; mt < 2; ++mt)
#pragma unroll
                for (int nt = 0; nt < 2; ++nt)
#pragma unroll
                    for (int q = 0; q < 4; ++q)
                        P[mt * 16 + lg * 4 + q][dg * 32 + nt * 16 + l15]
                            = acc[mt][nt][q] + (nt ? bv1 : bv0);
        }
        __syncthreads();
        if (kg == 1) {
#pragma unroll
            for (int mt = 0; mt < 2; ++mt)
#pragma unroll
                for (int nt = 0; nt < 2; ++nt)
#pragma unroll
                    for (int q = 0; q < 4; ++q)
                        P[mt * 16 + lg * 4 + q][dg * 32 + nt * 16 + l15]
                            += acc[mt][nt][q];
        }
        __syncthreads();
        if (kg == 2) {
#pragma unroll
            for (int mt = 0; mt < 2; ++mt)
#pragma unroll
                for (int nt = 0; nt < 2; ++nt)
#pragma unroll
                    for (int q = 0; q < 4; ++q)
                        P[mt * 16 + lg * 4 + q][dg * 32 + nt * 16 + l15]
                            += acc[mt][nt][q];
        }
        __syncthreads();

        // ---- L2-norm + mask + store (512 threads: row = tid>>4, 8 cols) ----
        if (tid < 512) {
            const int row = tid >> 4;
            const int c0  = (tid & 15) * 8;
            float v[8]; float ss = 0.f;
#pragma unroll
            for (int j = 0; j < 8; ++j) { v[j] = P[row][c0 + j]; ss += v[j] * v[j]; }
            ss += __shfl_xor(ss, 1);
            ss += __shfl_xor(ss, 2);
            ss += __shfl_xor(ss, 4);
            ss += __shfl_xor(ss, 8);
            float s = 1.0f / fmaxf(sqrtf(ss), 1e-12f);
            if (mask) s *= (float)mask[srow + row];
            unsigned short* op = emb + (size_t)(row0 + row) * D + c0;
#pragma unroll
            for (int j = 0; j < 8; ++j) op[j] = f2b(v[j] * s);
        }
        __syncthreads();   // P reusable next group
    }
}

// ---------------------------------------------------------------------------
// Kernel 3: MaxSim. One block per (batch, side); 4 waves x 128 doc tokens.
// ---------------------------------------------------------------------------
__global__ __launch_bounds__(256) void maxsim_kernel(
    const unsigned short* __restrict__ emb, float* __restrict__ out)
{
    const int blk  = blockIdx.x;       // 0..255
    const int b    = blk >> 1, side = blk & 1;
    const int wave = threadIdx.x >> 6, lane = threadIdx.x & 63;
    const int l15  = lane & 15, lg = lane >> 4;

    const unsigned short* Q  = emb + (size_t)(b * Lq) * D;
    const unsigned short* Dm = emb + (size_t)(QROWS + side * DROWS + b * Ld) * D;

    v4f acc[2][8];
#pragma unroll
    for (int m = 0; m < 2; ++m)
#pragma unroll
        for (int n = 0; n < 8; ++n) acc[m][n] = (v4f){0.f, 0.f, 0.f, 0.f};

    const int tok0 = wave * 128;
#pragma unroll
    for (int kk = 0; kk < 4; ++kk) {
        const int k0 = kk * 32 + lg * 8;
        v8s qa0 = *(const v8s*)(Q + (size_t)(l15) * D + k0);
        v8s qa1 = *(const v8s*)(Q + (size_t)(16 + l15) * D + k0);
#pragma unroll
        for (int n = 0; n < 8; ++n) {
            v8s db = *(const v8s*)(Dm + (size_t)(tok0 + n * 16 + l15) * D + k0);
            acc[0][n] = MFMA16(qa0, db, acc[0][n]);
            acc[1][n] = MFMA16(qa1, db, acc[1][n]);
        }
    }

    float mx[2][4];
#pragma unroll
    for (int m = 0; m < 2; ++m)
#pragma unroll
        for (int r = 0; r < 4; ++r) {
            float v = acc[m][0][r];
#pragma unroll
            for (int n = 1; n < 8; ++n) v = fmaxf(v, acc[m][n][r]);
            mx[m][r] = v;
        }
#pragma unroll
    for (int off = 1; off < 16; off <<= 1) {
#pragma unroll
        for (int m = 0; m < 2; ++m)
#pragma unroll
            for (int r = 0; r < 4; ++r)
                mx[m][r] = fmaxf(mx[m][r], __shfl_xor(mx[m][r], off));
    }

    __shared__ float red[4][32];
    if (l15 == 0) {
#pragma unroll
        for (int m = 0; m < 2; ++m)
#pragma unroll
            for (int r = 0; r < 4; ++r)
                red[wave][m * 16 + lg * 4 + r] = mx[m][r];
    }
    __syncthreads();

    if (threadIdx.x < 32) {
        int q = threadIdx.x;
        float v = fmaxf(fmaxf(red[0][q], red[1][q]), fmaxf(red[2][q], red[3][q]));
#pragma unroll
        for (int off = 1; off < 32; off <<= 1) v += __shfl_xor(v, off);
        if (q == 0) out[blk] = v;
    }
}

// ---------------------------------------------------------------------------
extern "C" void kernel_launch(void* const* d_in, const int* in_sizes, int n_in,
                              void* d_out, int out_size, void* d_ws, size_t ws_size,
                              hipStream_t stream)
{
    const float* qh   = (const float*)d_in[0];
    const float* pdh  = (const float*)d_in[1];
    const float* ndh  = (const float*)d_in[2];
    const float* W    = (const float*)d_in[3];
    const float* bias = (const float*)d_in[4];
    const int*   pdm  = (const int*)d_in[5];
    const int*   ndm  = (const int*)d_in[6];
    float* out = (float*)d_out;

    unsigned short* Wt  = (unsigned short*)d_ws;          // [D][H] bf16, 192 KB
    unsigned short* emb = Wt + (size_t)H * D;             // [MTOT][D] bf16

    prep_w_kernel<<<(H * D + 255) / 256, 256, 0, stream>>>(W, Wt);
    proj_norm_kernel<<<256, 768, 0, stream>>>(qh, pdh, ndh, bias, pdm, ndm, Wt, emb);
    maxsim_kernel<<<Bsz * 2, 256, 0, stream>>>(emb, out);
}

// Round 13
// 130.678 us; speedup vs baseline: 2.3300x; 2.3300x over previous
//
#include <hip/hip_runtime.h>
#include <hip/hip_bf16.h>

typedef short v8s __attribute__((ext_vector_type(8)));
typedef float v4f __attribute__((ext_vector_type(4)));

#define MFMA16(a, b, c) __builtin_amdgcn_mfma_f32_16x16x32_bf16((a), (b), (c), 0, 0, 0)

typedef __attribute__((address_space(1))) const void g_void;
typedef __attribute__((address_space(3))) void lds_void;
#define GLOAD_LDS16(g, l) \
    __builtin_amdgcn_global_load_lds((g_void*)(g), (lds_void*)(l), 16, 0, 0)

constexpr int Bsz   = 128;
constexpr int Lq    = 32;
constexpr int Ld    = 512;
constexpr int H     = 768;
constexpr int D     = 128;
constexpr int QROWS = Bsz * Lq;          // 4096
constexpr int DROWS = Bsz * Ld;          // 65536
constexpr int MTOT  = QROWS + 2 * DROWS; // 135168
constexpr int BM    = 64;                // rows per block
constexpr int BK    = 64;                // K per tile
constexpr int NT    = H / BK;            // 12 K-tiles
static_assert(QROWS % BM == 0 && DROWS % BM == 0, "block never spans sources");

// f32 -> bf16 bits, round-to-nearest-even
static __device__ __forceinline__ unsigned short f2b(float f) {
    unsigned int u = __builtin_bit_cast(unsigned int, f);
    unsigned int r = u + 0x7FFFu + ((u >> 16) & 1u);
    return (unsigned short)(r >> 16);
}
static __device__ __forceinline__ unsigned int pack2(float a, float b) {
    return (unsigned int)f2b(a) | ((unsigned int)f2b(b) << 16);
}

// ---------------------------------------------------------------------------
// Kernel 1: Wt[d][h] = bf16(W[h][d])
// ---------------------------------------------------------------------------
__global__ void prep_w_kernel(const float* __restrict__ W,
                              unsigned short* __restrict__ Wt) {
    int idx = blockIdx.x * 256 + threadIdx.x;
    if (idx < H * D) {
        int d = idx / H, h = idx % H;
        Wt[idx] = f2b(W[h * D + d]);
    }
}

// ---------------------------------------------------------------------------
// Kernel 2: projection.
//   A (HBM stream): register float4 loads (the R7-probe-fast path), converted
//   f32->bf16 ONCE at staging, ds_write into swizzled bf16 tile [64][64]
//   (8 KB, double-buffered).  W (L2-resident): global_load_lds DMA as R11.
//   K-loop never drains vmcnt: per iter
//     compute(t) -> vmcnt(4) [A regs t+1 ready; W-DMA t+1 in flight]
//     -> cvt+ds_write(t+1) -> issue A(t+2)+W-DMA(t+2) -> vmcnt(8)
//     [W(t+1) done, 8 loads stay in flight] -> lgkmcnt(0) -> s_barrier.
//   LDS 48.5 KB -> 3 blocks/CU. 4 waves: mg=row-half x ng=col-half.
// ---------------------------------------------------------------------------
__global__ __launch_bounds__(256, 4) void proj_norm_kernel(
    const float* __restrict__ qh, const float* __restrict__ pdh,
    const float* __restrict__ ndh, const float* __restrict__ bias,
    const int* __restrict__ pdm, const int* __restrict__ ndm,
    const unsigned short* __restrict__ Wt, unsigned short* __restrict__ emb)
{
    __shared__ unsigned short Abuf[2][BM * BK];   // 2 x 8 KB bf16
    __shared__ unsigned short Wbuf[2][D * BK];    // 2 x 16 KB bf16
    __shared__ float ssred[2][BM];

    const int tid  = threadIdx.x;
    const int lane = tid & 63, wave = tid >> 6;
    const int l15  = lane & 15, lg = lane >> 4;
    const int mg   = wave >> 1;                   // row half (32 rows)
    const int ng   = wave & 1;                    // col half (64 cols)
    const long row0 = (long)blockIdx.x * BM;

    const float* src; const int* mask; long srow;
    if (row0 < QROWS)              { src = qh;  srow = row0;                 mask = nullptr; }
    else if (row0 < QROWS + DROWS) { src = pdh; srow = row0 - QROWS;         mask = pdm; }
    else                           { src = ndh; srow = row0 - QROWS - DROWS; mask = ndm; }

    // ---- A register staging: thread -> row rr, 64 contiguous bytes ----
    const int rr = tid >> 2;                      // 0..63
    const int cc = tid & 3;                       // 16-float sub-block
    const float* gA = src + (srow + rr) * (long)H + cc * 16;

    float4 rA[4];                                 // in-flight A (one tile slice)

    auto issueA = [&](int kt) {
#pragma unroll
        for (int j = 0; j < 4; ++j)
            rA[j] = *(const float4*)(gA + kt * BK + j * 4);
    };
    // write: logical 8B slot c = cc*4+j, phys = c ^ ((rr&7)<<1)
    auto writeA = [&](int bi) {
#pragma unroll
        for (int j = 0; j < 4; ++j) {
            const int sl = (cc * 4 + j) ^ ((rr & 7) << 1);
            uint2 u;
            u.x = pack2(rA[j].x, rA[j].y);
            u.y = pack2(rA[j].z, rA[j].w);
            *(uint2*)(&Abuf[bi][rr * 64 + sl * 4]) = u;
        }
    };

    // ---- W DMA staging (R11-verified): wave stages 32 d-rows, 4 instrs ----
    auto stageW = [&](int bi, int kt) {
#pragma unroll
        for (int i = 0; i < 4; ++i) {
            const int d  = 32 * wave + 8 * i + (lane >> 3);
            const int cw = (lane & 7) ^ (lane >> 3);
            const unsigned short* gp = Wt + (size_t)d * H + kt * BK + cw * 8;
            GLOAD_LDS16(gp, &Wbuf[bi][(32 * wave + 8 * i) * BK]);
        }
    };

    v4f acc[2][4];
#pragma unroll
    for (int mt = 0; mt < 2; ++mt)
#pragma unroll
        for (int nt = 0; nt < 4; ++nt) acc[mt][nt] = (v4f){0.f, 0.f, 0.f, 0.f};

    auto compute = [&](int bi) {
#pragma unroll
        for (int kk = 0; kk < 2; ++kk) {
            v8s wfr[4];
#pragma unroll
            for (int nt = 0; nt < 4; ++nt) {
                const int d  = ng * 64 + nt * 16 + l15;
                const int ch = (kk * 4 + lg) ^ (l15 & 7);
                wfr[nt] = *(const v8s*)(&Wbuf[bi][d * BK + ch * 8]);
            }
#pragma unroll
            for (int mt = 0; mt < 2; ++mt) {
                const int r  = mg * 32 + mt * 16 + l15;
                const int ch = (kk * 4 + lg) ^ (r & 7);
                v8s a = *(const v8s*)(&Abuf[bi][r * 64 + ch * 8]);
#pragma unroll
                for (int nt = 0; nt < 4; ++nt)
                    acc[mt][nt] = MFMA16(a, wfr[nt], acc[mt][nt]);
            }
        }
    };

    // ---- prologue: tile0 staged+written, tile1 in flight ----
    issueA(0); stageW(0, 0);                       // FIFO: A0(4), W0(4)
    asm volatile("s_waitcnt vmcnt(4)" ::: "memory");   // A0 regs ready
    writeA(0);
    issueA(1); stageW(1, 1);                       // FIFO: W0(4), A1(4), W1(4)
    asm volatile("s_waitcnt vmcnt(8)" ::: "memory");   // W0 done
    asm volatile("s_waitcnt lgkmcnt(0)" ::: "memory"); // A0 writes done
    __builtin_amdgcn_sched_barrier(0);
    __builtin_amdgcn_s_barrier();                  // tile0 ready

#pragma unroll
    for (int t = 0; t < NT; ++t) {
        compute(t & 1);
        if (t + 1 < NT) {
            __builtin_amdgcn_sched_barrier(0);
            asm volatile("s_waitcnt vmcnt(4)" ::: "memory");   // A(t+1) ready
            writeA((t + 1) & 1);
            if (t + 2 < NT) {
                issueA(t + 2);
                stageW(t & 1 /* == (t+2)&1 */, t + 2);
                asm volatile("s_waitcnt vmcnt(8)" ::: "memory"); // W(t+1) done
            } else {
                asm volatile("s_waitcnt vmcnt(0)" ::: "memory"); // tail drain
            }
            asm volatile("s_waitcnt lgkmcnt(0)" ::: "memory");   // my ds_writes
            __builtin_amdgcn_sched_barrier(0);
            __builtin_amdgcn_s_barrier();          // tile t+1 ready
        }
    }

    // ---- epilogue: bias, cross-ng L2-norm, mask, store bf16 ----
    float bv[4];
#pragma unroll
    for (int nt = 0; nt < 4; ++nt) bv[nt] = bias[ng * 64 + nt * 16 + l15];

    float ss[2][4];
#pragma unroll
    for (int mt = 0; mt < 2; ++mt)
#pragma unroll
        for (int q = 0; q < 4; ++q) {
            float s = 0.f;
#pragma unroll
            for (int nt = 0; nt < 4; ++nt) {
                float v = acc[mt][nt][q] + bv[nt];
                acc[mt][nt][q] = v;
                s += v * v;
            }
            ss[mt][q] = s;
        }
#pragma unroll
    for (int off = 1; off < 16; off <<= 1)
#pragma unroll
        for (int mt = 0; mt < 2; ++mt)
#pragma unroll
            for (int q = 0; q < 4; ++q)
                ss[mt][q] += __shfl_xor(ss[mt][q], off);

    if (l15 == 0) {
#pragma unroll
        for (int mt = 0; mt < 2; ++mt)
#pragma unroll
            for (int q = 0; q < 4; ++q)
                ssred[ng][mg * 32 + mt * 16 + lg * 4 + q] = ss[mt][q];
    }
    __syncthreads();   // nothing in flight now; full sync is safe

#pragma unroll
    for (int mt = 0; mt < 2; ++mt)
#pragma unroll
        for (int q = 0; q < 4; ++q) {
            const int row = mg * 32 + mt * 16 + lg * 4 + q;
            float t = ssred[0][row] + ssred[1][row];
            float s = 1.0f / fmaxf(sqrtf(t), 1e-12f);
            if (mask) s *= (float)mask[srow + row];
            unsigned short* op = emb + (size_t)(row0 + row) * D + ng * 64 + l15;
#pragma unroll
            for (int nt = 0; nt < 4; ++nt)
                op[nt * 16] = f2b(acc[mt][nt][q] * s);
        }
}

// ---------------------------------------------------------------------------
// Kernel 3: MaxSim. One block per (batch, side); 4 waves x 128 doc tokens.
// ---------------------------------------------------------------------------
__global__ __launch_bounds__(256) void maxsim_kernel(
    const unsigned short* __restrict__ emb, float* __restrict__ out)
{
    const int blk  = blockIdx.x;       // 0..255
    const int b    = blk >> 1, side = blk & 1;
    const int wave = threadIdx.x >> 6, lane = threadIdx.x & 63;
    const int l15  = lane & 15, lg = lane >> 4;

    const unsigned short* Q  = emb + (size_t)(b * Lq) * D;
    const unsigned short* Dm = emb + (size_t)(QROWS + side * DROWS + b * Ld) * D;

    v4f acc[2][8];
#pragma unroll
    for (int m = 0; m < 2; ++m)
#pragma unroll
        for (int n = 0; n < 8; ++n) acc[m][n] = (v4f){0.f, 0.f, 0.f, 0.f};

    const int tok0 = wave * 128;
#pragma unroll
    for (int kk = 0; kk < 4; ++kk) {
        const int k0 = kk * 32 + lg * 8;
        v8s qa0 = *(const v8s*)(Q + (size_t)(l15) * D + k0);
        v8s qa1 = *(const v8s*)(Q + (size_t)(16 + l15) * D + k0);
#pragma unroll
        for (int n = 0; n < 8; ++n) {
            v8s db = *(const v8s*)(Dm + (size_t)(tok0 + n * 16 + l15) * D + k0);
            acc[0][n] = MFMA16(qa0, db, acc[0][n]);
            acc[1][n] = MFMA16(qa1, db, acc[1][n]);
        }
    }

    float mx[2][4];
#pragma unroll
    for (int m = 0; m < 2; ++m)
#pragma unroll
        for (int r = 0; r < 4; ++r) {
            float v = acc[m][0][r];
#pragma unroll
            for (int n = 1; n < 8; ++n) v = fmaxf(v, acc[m][n][r]);
            mx[m][r] = v;
        }
#pragma unroll
    for (int off = 1; off < 16; off <<= 1) {
#pragma unroll
        for (int m = 0; m < 2; ++m)
#pragma unroll
            for (int r = 0; r < 4; ++r)
                mx[m][r] = fmaxf(mx[m][r], __shfl_xor(mx[m][r], off));
    }

    __shared__ float red[4][32];
    if (l15 == 0) {
#pragma unroll
        for (int m = 0; m < 2; ++m)
#pragma unroll
            for (int r = 0; r < 4; ++r)
                red[wave][m * 16 + lg * 4 + r] = mx[m][r];
    }
    __syncthreads();

    if (threadIdx.x < 32) {
        int q = threadIdx.x;
        float v = fmaxf(fmaxf(red[0][q], red[1][q]), fmaxf(red[2][q], red[3][q]));
#pragma unroll
        for (int off = 1; off < 32; off <<= 1) v += __shfl_xor(v, off);
        if (q == 0) out[blk] = v;
    }
}

// ---------------------------------------------------------------------------
extern "C" void kernel_launch(void* const* d_in, const int* in_sizes, int n_in,
                              void* d_out, int out_size, void* d_ws, size_t ws_size,
                              hipStream_t stream)
{
    const float* qh   = (const float*)d_in[0];
    const float* pdh  = (const float*)d_in[1];
    const float* ndh  = (const float*)d_in[2];
    const float* W    = (const float*)d_in[3];
    const float* bias = (const float*)d_in[4];
    const int*   pdm  = (const int*)d_in[5];
    const int*   ndm  = (const int*)d_in[6];
    float* out = (float*)d_out;

    unsigned short* Wt  = (unsigned short*)d_ws;          // [D][H] bf16, 192 KB
    unsigned short* emb = Wt + (size_t)H * D;             // [MTOT][D] bf16

    prep_w_kernel<<<(H * D + 255) / 256, 256, 0, stream>>>(W, Wt);
    proj_norm_kernel<<<MTOT / BM, 256, 0, stream>>>(qh, pdh, ndh, bias, pdm, ndm, Wt, emb);
    maxsim_kernel<<<Bsz * 2, 256, 0, stream>>>(emb, out);
}